// Round 5
// baseline (2245.318 us; speedup 1.0000x reference)
//
#include <hip/hip_runtime.h>
#include <hip/hip_bf16.h>
#include <stdint.h>

#define D 128
#define NUM_HOPS 8
#define SCAN_BS 256
#define SCAN2_BS 512

// ---------------- Threefry-2x32 (matches jax._src.prng) ----------------
__host__ __device__ inline void tf2x32(uint32_t k0, uint32_t k1,
                                       uint32_t x0, uint32_t x1,
                                       uint32_t* o0, uint32_t* o1) {
  uint32_t ks2 = k0 ^ k1 ^ 0x1BD11BDAu;
  x0 += k0; x1 += k1;
#define TF_RND(r) { x0 += x1; x1 = (x1 << r) | (x1 >> (32 - r)); x1 ^= x0; }
  TF_RND(13) TF_RND(15) TF_RND(26) TF_RND(6)
  x0 += k1; x1 += ks2 + 1u;
  TF_RND(17) TF_RND(29) TF_RND(16) TF_RND(24)
  x0 += ks2; x1 += k0 + 2u;
  TF_RND(13) TF_RND(15) TF_RND(26) TF_RND(6)
  x0 += k0; x1 += k1 + 3u;
  TF_RND(17) TF_RND(29) TF_RND(16) TF_RND(24)
  x0 += k1; x1 += ks2 + 4u;
  TF_RND(13) TF_RND(15) TF_RND(26) TF_RND(6)
  x0 += ks2; x1 += k0 + 5u;
#undef TF_RND
  *o0 = x0; *o1 = x1;
}

// XLA ErfInv32 (Giles polynomial, w = -log1p(-x*x))
__device__ inline float erfinv_f32(float x) {
  float w = -log1pf(-x * x);
  float p;
  if (w < 5.0f) {
    w = w - 2.5f;
    p = 2.81022636e-08f;
    p = fmaf(p, w, 3.43273939e-07f);
    p = fmaf(p, w, -3.5233877e-06f);
    p = fmaf(p, w, -4.39150654e-06f);
    p = fmaf(p, w, 0.00021858087f);
    p = fmaf(p, w, -0.00125372503f);
    p = fmaf(p, w, -0.00417768164f);
    p = fmaf(p, w, 0.246640727f);
    p = fmaf(p, w, 1.50140941f);
  } else {
    w = sqrtf(w) - 3.0f;
    p = -0.000200214257f;
    p = fmaf(p, w, 0.000100950558f);
    p = fmaf(p, w, 0.00134934322f);
    p = fmaf(p, w, -0.00367342844f);
    p = fmaf(p, w, 0.00573950773f);
    p = fmaf(p, w, -0.0076224613f);
    p = fmaf(p, w, 0.00943887047f);
    p = fmaf(p, w, 1.00167406f);
    p = fmaf(p, w, 2.83297682f);
  }
  return p * x;
}

__device__ inline float noise_from_bits(uint32_t bits) {
  const float lo = -0.99999994f;            // nextafter(-1,0) in f32
  uint32_t fb = (bits >> 9) | 0x3f800000u;
  float f = __uint_as_float(fb) - 1.0f;     // [0,1)
  float u = fmaxf(lo, fmaf(f, 2.0f, lo));   // hi-lo rounds to exactly 2.0f
  return 0.1f * (1.41421354f * erfinv_f32(u));
}

// Partitionable threefry element t: bits = w0 ^ w1 of tf(key, t>>32, t&0xffffffff)
__device__ inline float noise_elem(uint32_t fk0, uint32_t fk1, long t) {
  uint32_t o0, o1;
  tf2x32(fk0, fk1, (uint32_t)(((unsigned long)t) >> 32), (uint32_t)t, &o0, &o1);
  return noise_from_bits(o0 ^ o1);
}

// Detect int64 edge_index passed raw (odd int32 slots all-zero high words).
__device__ inline bool edges_are_i64(const int* __restrict__ ei) {
  return (ei[1] | ei[3] | ei[5] | ei[7] | ei[9] | ei[11] | ei[13] | ei[15]) == 0;
}

// ---------------- CSR build ----------------
__global__ __launch_bounds__(256) void hist_kernel(const int* __restrict__ ei,
                                                   int* __restrict__ counts, long E) {
  long e = (long)blockIdx.x * blockDim.x + threadIdx.x;
  if (e >= E) return;
  bool i64 = edges_are_i64(ei);
  int d = __builtin_nontemporal_load(&ei[i64 ? (2 * (E + e)) : (E + e)]);
  atomicAdd(&counts[d], 1);
}

// exclusive scan within 256-chunk; chunk totals to partials
__global__ __launch_bounds__(SCAN_BS) void scan1_kernel(const int* __restrict__ counts,
                                                        int* __restrict__ excl,
                                                        int* __restrict__ partials, int N) {
  __shared__ int lds[SCAN_BS];
  int tid = threadIdx.x;
  int i = blockIdx.x * SCAN_BS + tid;
  int v = (i < N) ? counts[i] : 0;
  lds[tid] = v;
  __syncthreads();
  for (int off = 1; off < SCAN_BS; off <<= 1) {
    int t = (tid >= off) ? lds[tid - off] : 0;
    __syncthreads();
    if (tid >= off) lds[tid] += t;
    __syncthreads();
  }
  int incl = lds[tid];
  if (i < N) excl[i] = incl - v;
  if (tid == SCAN_BS - 1) partials[blockIdx.x] = incl;
}

// exclusive scan of partials (nchunks <= SCAN2_BS), in place
__global__ __launch_bounds__(SCAN2_BS) void scan2_kernel(int* __restrict__ partials, int nchunks) {
  __shared__ int lds[SCAN2_BS];
  int tid = threadIdx.x;
  int v = (tid < nchunks) ? partials[tid] : 0;
  lds[tid] = v;
  __syncthreads();
  for (int off = 1; off < SCAN2_BS; off <<= 1) {
    int t = (tid >= off) ? lds[tid - off] : 0;
    __syncthreads();
    if (tid >= off) lds[tid] += t;
    __syncthreads();
  }
  if (tid < nchunks) partials[tid] = lds[tid] - v;  // exclusive
}

// row_ptr[i] = excl[i] + partials[i/256]; cursor[i] = row_ptr[i]; row_ptr[N] = E
__global__ __launch_bounds__(256) void scan3_kernel(int* __restrict__ row_ptr,
                                                    const int* __restrict__ partials,
                                                    int* __restrict__ cursor, int N, int E) {
  int i = blockIdx.x * blockDim.x + threadIdx.x;
  if (i > N) return;
  if (i == N) { row_ptr[N] = E; return; }
  int v = row_ptr[i] + partials[i >> 8];
  row_ptr[i] = v;
  cursor[i] = v;
}

// NT loads of ei keep L2 clean so dirty col lines can coalesce before eviction.
__global__ __launch_bounds__(256) void fill_kernel(const int* __restrict__ ei,
                                                   int* __restrict__ cursor,
                                                   int* __restrict__ col, long E) {
  long e = (long)blockIdx.x * blockDim.x + threadIdx.x;
  if (e >= E) return;
  bool i64 = edges_are_i64(ei);
  int s = __builtin_nontemporal_load(&ei[i64 ? (2 * e) : e]);
  int d = __builtin_nontemporal_load(&ei[i64 ? (2 * (E + e)) : (E + e)]);
  int slot = atomicAdd(&cursor[d], 1);
  col[slot] = s;
}

// ---------------- Fused per-hop: noise + CSR gather + L2 normalize ----------------
// One wave per destination row; half-wave float4 layout: lanes 0-31 take even
// col slots, lanes 32-63 odd slots; each half reads a full 512B source row as
// 32 x float4. Halves combined with one shfl_xor(.,32) at the end.
__global__ __launch_bounds__(256) void gather_hop(const float* __restrict__ cur,
                                                  float* __restrict__ nxt,
                                                  const int* __restrict__ row_ptr,
                                                  const int* __restrict__ col,
                                                  int N, uint32_t fk0, uint32_t fk1) {
  long t = (long)blockIdx.x * blockDim.x + threadIdx.x;
  int row = (int)(t >> 6);
  if (row >= N) return;
  int lane = (int)(t & 63);
  int half = lane >> 5;
  int l32 = lane & 31;

  float4 acc = make_float4(0.f, 0.f, 0.f, 0.f);
  int beg = row_ptr[row], end = row_ptr[row + 1];

  int i = beg + half;
  // 4-deep pipeline: 4 independent col->row chains in flight per half-wave
  for (; i + 6 < end; i += 8) {
    int s0 = __builtin_nontemporal_load(&col[i]);
    int s1 = __builtin_nontemporal_load(&col[i + 2]);
    int s2 = __builtin_nontemporal_load(&col[i + 4]);
    int s3 = __builtin_nontemporal_load(&col[i + 6]);
    float4 v0 = ((const float4*)(cur + (size_t)s0 * D))[l32];
    float4 v1 = ((const float4*)(cur + (size_t)s1 * D))[l32];
    float4 v2 = ((const float4*)(cur + (size_t)s2 * D))[l32];
    float4 v3 = ((const float4*)(cur + (size_t)s3 * D))[l32];
    acc.x += v0.x + v1.x + v2.x + v3.x;
    acc.y += v0.y + v1.y + v2.y + v3.y;
    acc.z += v0.z + v1.z + v2.z + v3.z;
    acc.w += v0.w + v1.w + v2.w + v3.w;
  }
  for (; i < end; i += 2) {
    int s = __builtin_nontemporal_load(&col[i]);
    float4 v = ((const float4*)(cur + (size_t)s * D))[l32];
    acc.x += v.x; acc.y += v.y; acc.z += v.z; acc.w += v.w;
  }

  // combine the two halves (each covers all 128 columns over its slot subset)
  acc.x += __shfl_xor(acc.x, 32, 64);
  acc.y += __shfl_xor(acc.y, 32, 64);
  acc.z += __shfl_xor(acc.z, 32, 64);
  acc.w += __shfl_xor(acc.w, 32, 64);

  // noise (both halves compute identical values; harmless, keeps wave uniform)
  long t0 = (long)row * D + l32 * 4;
  acc.x += noise_elem(fk0, fk1, t0);
  acc.y += noise_elem(fk0, fk1, t0 + 1);
  acc.z += noise_elem(fk0, fk1, t0 + 2);
  acc.w += noise_elem(fk0, fk1, t0 + 3);

  float ss = acc.x * acc.x + acc.y * acc.y + acc.z * acc.z + acc.w * acc.w;
  #pragma unroll
  for (int off = 16; off > 0; off >>= 1) ss += __shfl_xor(ss, off, 64);
  float inv = 1.0f / fmaxf(sqrtf(ss), 1e-12f);

  if (half == 0) {
    float4 o;
    o.x = acc.x * inv; o.y = acc.y * inv; o.z = acc.z * inv; o.w = acc.w * inv;
    ((float4*)(nxt + (size_t)row * D))[l32] = o;
  }
}

// ---------------- Fallback path kernels (round-3, atomic scatter) ----------------
__global__ __launch_bounds__(256) void noise_kernel(float* __restrict__ out,
                                                    uint32_t fk0, uint32_t fk1, long n) {
  long t = (long)blockIdx.x * blockDim.x + threadIdx.x;
  if (t >= n) return;
  out[t] = noise_elem(fk0, fk1, t);
}

__global__ __launch_bounds__(256) void scatter_kernel(const float* __restrict__ cur,
                                                      float* __restrict__ aggr,
                                                      const int* __restrict__ ei, long E) {
  long tid = (long)blockIdx.x * blockDim.x + threadIdx.x;
  long e = tid >> 5;
  if (e >= E) return;
  int lane = (int)(tid & 31);
  bool i64 = edges_are_i64(ei);
  int s = ei[i64 ? (2 * e) : e];
  int d = ei[i64 ? (2 * (E + e)) : (E + e)];
  float4 v = *(const float4*)(cur + (size_t)s * D + lane * 4);
  float* dp = aggr + (size_t)d * D + lane * 4;
  unsafeAtomicAdd(dp + 0, v.x);
  unsafeAtomicAdd(dp + 1, v.y);
  unsafeAtomicAdd(dp + 2, v.z);
  unsafeAtomicAdd(dp + 3, v.w);
}

// Row L2-normalize; one wave per row. in==out OK.
__global__ __launch_bounds__(256) void norm_kernel(const float* __restrict__ in,
                                                   float* __restrict__ out, int N) {
  long t = (long)blockIdx.x * blockDim.x + threadIdx.x;
  int row = (int)(t >> 6);
  int lane = (int)(t & 63);
  if (row >= N) return;
  float2 v = *(const float2*)(in + (size_t)row * D + lane * 2);
  float s = v.x * v.x + v.y * v.y;
  #pragma unroll
  for (int off = 32; off > 0; off >>= 1) s += __shfl_xor(s, off, 64);
  float inv = 1.0f / fmaxf(sqrtf(s), 1e-12f);
  float2 o; o.x = v.x * inv; o.y = v.y * inv;
  *(float2*)(out + (size_t)row * D + lane * 2) = o;
}

extern "C" void kernel_launch(void* const* d_in, const int* in_sizes, int n_in,
                              void* d_out, int out_size, void* d_ws, size_t ws_size,
                              hipStream_t stream) {
  const float* x = (const float*)d_in[0];
  const int* ei = (const int*)d_in[1];
  const long N = in_sizes[0] / D;      // 100000
  const long E = in_sizes[1] / 2;      // 3200000
  float* out = (float*)d_out;
  const long ND = N * D;

  // folded keys: fold_in(key(42), k) = threefry2x32((0,42), (0,k))
  uint32_t fk0[NUM_HOPS], fk1[NUM_HOPS];
  for (int k = 0; k < NUM_HOPS; ++k)
    tf2x32(0u, 42u, 0u, (uint32_t)k, &fk0[k], &fk1[k]);

  // hop 0: normalize x -> out[0]
  {
    long threads = N * 64;
    norm_kernel<<<(int)((threads + 255) / 256), 256, 0, stream>>>(x, out, (int)N);
  }

  // Workspace layout (ints): row_ptr[N+1] | counts[N] (reused as cursor) | partials[nchunks] | col[E]
  const int nchunks = (int)((N + SCAN_BS - 1) / SCAN_BS);
  size_t need = ((size_t)(N + 1) + (size_t)N + (size_t)nchunks + (size_t)E) * sizeof(int);

  if (ws_size >= need && nchunks <= SCAN2_BS) {
    int* row_ptr  = (int*)d_ws;
    int* counts   = row_ptr + (N + 1);     // later reused as cursor
    int* partials = counts + N;
    int* col      = partials + nchunks;

    hipMemsetAsync(counts, 0, (size_t)N * sizeof(int), stream);
    hist_kernel<<<(int)((E + 255) / 256), 256, 0, stream>>>(ei, counts, E);
    scan1_kernel<<<nchunks, SCAN_BS, 0, stream>>>(counts, row_ptr, partials, (int)N);
    scan2_kernel<<<1, SCAN2_BS, 0, stream>>>(partials, nchunks);
    scan3_kernel<<<(int)((N + 256) / 256), 256, 0, stream>>>(row_ptr, partials, counts, (int)N, (int)E);
    fill_kernel<<<(int)((E + 255) / 256), 256, 0, stream>>>(ei, counts, col, E);

    long nthreads = N * 64;
    int ngrid = (int)((nthreads + 255) / 256);
    for (int k = 0; k < NUM_HOPS; ++k) {
      const float* cur = out + (size_t)k * ND;
      float* nxt = out + (size_t)(k + 1) * ND;
      gather_hop<<<ngrid, 256, 0, stream>>>(cur, nxt, row_ptr, col, (int)N, fk0[k], fk1[k]);
    }
  } else {
    // Fallback: proven round-3 atomic path
    for (int k = 0; k < NUM_HOPS; ++k) {
      const float* cur = out + (size_t)k * ND;
      float* nxt = out + (size_t)(k + 1) * ND;
      noise_kernel<<<(int)((ND + 255) / 256), 256, 0, stream>>>(nxt, fk0[k], fk1[k], ND);
      long sthreads = E * 32;
      scatter_kernel<<<(int)((sthreads + 255) / 256), 256, 0, stream>>>(cur, nxt, ei, E);
      long nthreads = N * 64;
      norm_kernel<<<(int)((nthreads + 255) / 256), 256, 0, stream>>>(nxt, nxt, (int)N);
    }
  }
}

// Round 6
// 1583.705 us; speedup vs baseline: 1.4178x; 1.4178x over previous
//
#include <hip/hip_runtime.h>
#include <hip/hip_bf16.h>
#include <hip/hip_fp16.h>
#include <stdint.h>

#define D 128
#define NUM_HOPS 8
#define SCAN_BS 256
#define SCAN2_BS 512

// ---------------- Threefry-2x32 (matches jax._src.prng) ----------------
__host__ __device__ inline void tf2x32(uint32_t k0, uint32_t k1,
                                       uint32_t x0, uint32_t x1,
                                       uint32_t* o0, uint32_t* o1) {
  uint32_t ks2 = k0 ^ k1 ^ 0x1BD11BDAu;
  x0 += k0; x1 += k1;
#define TF_RND(r) { x0 += x1; x1 = (x1 << r) | (x1 >> (32 - r)); x1 ^= x0; }
  TF_RND(13) TF_RND(15) TF_RND(26) TF_RND(6)
  x0 += k1; x1 += ks2 + 1u;
  TF_RND(17) TF_RND(29) TF_RND(16) TF_RND(24)
  x0 += ks2; x1 += k0 + 2u;
  TF_RND(13) TF_RND(15) TF_RND(26) TF_RND(6)
  x0 += k0; x1 += k1 + 3u;
  TF_RND(17) TF_RND(29) TF_RND(16) TF_RND(24)
  x0 += k1; x1 += ks2 + 4u;
  TF_RND(13) TF_RND(15) TF_RND(26) TF_RND(6)
  x0 += ks2; x1 += k0 + 5u;
#undef TF_RND
  *o0 = x0; *o1 = x1;
}

// XLA ErfInv32 (Giles polynomial, w = -log1p(-x*x))
__device__ inline float erfinv_f32(float x) {
  float w = -log1pf(-x * x);
  float p;
  if (w < 5.0f) {
    w = w - 2.5f;
    p = 2.81022636e-08f;
    p = fmaf(p, w, 3.43273939e-07f);
    p = fmaf(p, w, -3.5233877e-06f);
    p = fmaf(p, w, -4.39150654e-06f);
    p = fmaf(p, w, 0.00021858087f);
    p = fmaf(p, w, -0.00125372503f);
    p = fmaf(p, w, -0.00417768164f);
    p = fmaf(p, w, 0.246640727f);
    p = fmaf(p, w, 1.50140941f);
  } else {
    w = sqrtf(w) - 3.0f;
    p = -0.000200214257f;
    p = fmaf(p, w, 0.000100950558f);
    p = fmaf(p, w, 0.00134934322f);
    p = fmaf(p, w, -0.00367342844f);
    p = fmaf(p, w, 0.00573950773f);
    p = fmaf(p, w, -0.0076224613f);
    p = fmaf(p, w, 0.00943887047f);
    p = fmaf(p, w, 1.00167406f);
    p = fmaf(p, w, 2.83297682f);
  }
  return p * x;
}

__device__ inline float noise_from_bits(uint32_t bits) {
  const float lo = -0.99999994f;            // nextafter(-1,0) in f32
  uint32_t fb = (bits >> 9) | 0x3f800000u;
  float f = __uint_as_float(fb) - 1.0f;     // [0,1)
  float u = fmaxf(lo, fmaf(f, 2.0f, lo));   // hi-lo rounds to exactly 2.0f
  return 0.1f * (1.41421354f * erfinv_f32(u));
}

// Partitionable threefry element t: bits = w0 ^ w1 of tf(key, t>>32, t&0xffffffff)
__device__ inline float noise_elem(uint32_t fk0, uint32_t fk1, long t) {
  uint32_t o0, o1;
  tf2x32(fk0, fk1, (uint32_t)(((unsigned long)t) >> 32), (uint32_t)t, &o0, &o1);
  return noise_from_bits(o0 ^ o1);
}

// Detect int64 edge_index passed raw (odd int32 slots all-zero high words).
__device__ inline bool edges_are_i64(const int* __restrict__ ei) {
  return (ei[1] | ei[3] | ei[5] | ei[7] | ei[9] | ei[11] | ei[13] | ei[15]) == 0;
}

// ---------------- CSR build ----------------
__global__ __launch_bounds__(256) void hist_kernel(const int* __restrict__ ei,
                                                   int* __restrict__ counts, long E) {
  long e = (long)blockIdx.x * blockDim.x + threadIdx.x;
  if (e >= E) return;
  bool i64 = edges_are_i64(ei);
  int d = __builtin_nontemporal_load(&ei[i64 ? (2 * (E + e)) : (E + e)]);
  atomicAdd(&counts[d], 1);
}

__global__ __launch_bounds__(SCAN_BS) void scan1_kernel(const int* __restrict__ counts,
                                                        int* __restrict__ excl,
                                                        int* __restrict__ partials, int N) {
  __shared__ int lds[SCAN_BS];
  int tid = threadIdx.x;
  int i = blockIdx.x * SCAN_BS + tid;
  int v = (i < N) ? counts[i] : 0;
  lds[tid] = v;
  __syncthreads();
  for (int off = 1; off < SCAN_BS; off <<= 1) {
    int t = (tid >= off) ? lds[tid - off] : 0;
    __syncthreads();
    if (tid >= off) lds[tid] += t;
    __syncthreads();
  }
  int incl = lds[tid];
  if (i < N) excl[i] = incl - v;
  if (tid == SCAN_BS - 1) partials[blockIdx.x] = incl;
}

__global__ __launch_bounds__(SCAN2_BS) void scan2_kernel(int* __restrict__ partials, int nchunks) {
  __shared__ int lds[SCAN2_BS];
  int tid = threadIdx.x;
  int v = (tid < nchunks) ? partials[tid] : 0;
  lds[tid] = v;
  __syncthreads();
  for (int off = 1; off < SCAN2_BS; off <<= 1) {
    int t = (tid >= off) ? lds[tid - off] : 0;
    __syncthreads();
    if (tid >= off) lds[tid] += t;
    __syncthreads();
  }
  if (tid < nchunks) partials[tid] = lds[tid] - v;  // exclusive
}

__global__ __launch_bounds__(256) void scan3_kernel(int* __restrict__ row_ptr,
                                                    const int* __restrict__ partials,
                                                    int* __restrict__ cursor, int N, int E) {
  int i = blockIdx.x * blockDim.x + threadIdx.x;
  if (i > N) return;
  if (i == N) { row_ptr[N] = E; return; }
  int v = row_ptr[i] + partials[i >> 8];
  row_ptr[i] = v;
  cursor[i] = v;
}

__global__ __launch_bounds__(256) void fill_kernel(const int* __restrict__ ei,
                                                   int* __restrict__ cursor,
                                                   int* __restrict__ col, long E) {
  long e = (long)blockIdx.x * blockDim.x + threadIdx.x;
  if (e >= E) return;
  bool i64 = edges_are_i64(ei);
  int s = __builtin_nontemporal_load(&ei[i64 ? (2 * e) : e]);
  int d = __builtin_nontemporal_load(&ei[i64 ? (2 * (E + e)) : (E + e)]);
  int slot = atomicAdd(&cursor[d], 1);
  col[slot] = s;
}

// ---------------- hop 0: normalize x -> out[0] (f32) + mirror (f16) ----------------
__global__ __launch_bounds__(256) void norm0_kernel(const float* __restrict__ in,
                                                    float* __restrict__ out,
                                                    __half* __restrict__ mir, int N) {
  long t = (long)blockIdx.x * blockDim.x + threadIdx.x;
  int row = (int)(t >> 6);
  int lane = (int)(t & 63);
  if (row >= N) return;
  float2 v = *(const float2*)(in + (size_t)row * D + lane * 2);
  float s = v.x * v.x + v.y * v.y;
  #pragma unroll
  for (int off = 32; off > 0; off >>= 1) s += __shfl_xor(s, off, 64);
  float inv = 1.0f / fmaxf(sqrtf(s), 1e-12f);
  float2 o; o.x = v.x * inv; o.y = v.y * inv;
  *(float2*)(out + (size_t)row * D + lane * 2) = o;
  __half2 h = __float22half2_rn(o);
  ((uint32_t*)mir)[(size_t)row * 64 + lane] = *(const uint32_t*)&h;
}

// ---------------- Fused per-hop (f16 mirror): noise + gather + normalize ----------------
// Quarter-wave layout: quarter q (16 lanes) reads one 256B f16 source row per
// VMEM instr (lane l16 holds elems [l16*8, l16*8+8)). Quarters combined via
// shfl_xor(16,32). Noise: 2 threefry/lane (elems 2*lane, 2*lane+1), routed to
// chunk owners with 8 shfls. Accumulation entirely f32.
__global__ __launch_bounds__(256) void gather_hop_f16(const __half* __restrict__ mirIn,
                                                      float* __restrict__ nxt,
                                                      __half* __restrict__ mirOut,
                                                      const int* __restrict__ row_ptr,
                                                      const int* __restrict__ col,
                                                      int N, uint32_t fk0, uint32_t fk1) {
  long t = (long)blockIdx.x * blockDim.x + threadIdx.x;
  int row = (int)(t >> 6);
  if (row >= N) return;
  int lane = (int)(t & 63);
  int q = lane >> 4;
  int l16 = lane & 15;

  // noise for elems {2*lane, 2*lane+1} — computed once per wave per element
  long t0 = (long)row * D + 2 * lane;
  float n0 = noise_elem(fk0, fk1, t0);
  float n1 = noise_elem(fk0, fk1, t0 + 1);

  float acc[8];
  #pragma unroll
  for (int j = 0; j < 8; ++j) acc[j] = 0.f;

  auto acc8 = [&](uint4 a) {
    const __half2* hp = (const __half2*)&a;
    #pragma unroll
    for (int j = 0; j < 4; ++j) {
      float2 f = __half22float2(hp[j]);
      acc[2 * j]     += f.x;
      acc[2 * j + 1] += f.y;
    }
  };

  const uint4* mir4 = (const uint4*)mirIn;   // 16 uint4 per row
  int beg = row_ptr[row], end = row_ptr[row + 1];
  int i = beg + q;
  for (; i + 4 < end; i += 8) {              // 2 rows in flight per quarter
    int s0 = col[i];
    int s1 = col[i + 4];
    uint4 a = mir4[(size_t)s0 * 16 + l16];
    uint4 b = mir4[(size_t)s1 * 16 + l16];
    acc8(a); acc8(b);
  }
  for (; i < end; i += 4) {
    int s = col[i];
    acc8(mir4[(size_t)s * 16 + l16]);
  }

  // combine quarters: every lane ends with the full row-sum for chunk l16
  #pragma unroll
  for (int j = 0; j < 8; ++j) {
    acc[j] += __shfl_xor(acc[j], 16, 64);
    acc[j] += __shfl_xor(acc[j], 32, 64);
  }

  // add noise: elem l16*8+j was computed on lane (l16*8+j)>>1, component j&1
  #pragma unroll
  for (int j = 0; j < 8; ++j) {
    int src = (l16 << 2) | (j >> 1);
    acc[j] += __shfl((j & 1) ? n1 : n0, src, 64);
  }

  float ss = 0.f;
  #pragma unroll
  for (int j = 0; j < 8; ++j) ss += acc[j] * acc[j];
  ss += __shfl_xor(ss, 1, 64);
  ss += __shfl_xor(ss, 2, 64);
  ss += __shfl_xor(ss, 4, 64);
  ss += __shfl_xor(ss, 8, 64);
  float inv = 1.0f / fmaxf(sqrtf(ss), 1e-12f);
  #pragma unroll
  for (int j = 0; j < 8; ++j) acc[j] *= inv;

  if (q == 0) {                              // f32 output row (512B)
    float4* op = (float4*)(nxt + (size_t)row * D + l16 * 8);
    op[0] = make_float4(acc[0], acc[1], acc[2], acc[3]);
    op[1] = make_float4(acc[4], acc[5], acc[6], acc[7]);
  } else if (q == 1) {                       // f16 mirror row (256B), parallel store
    __half2 h0 = __float22half2_rn(make_float2(acc[0], acc[1]));
    __half2 h1 = __float22half2_rn(make_float2(acc[2], acc[3]));
    __half2 h2 = __float22half2_rn(make_float2(acc[4], acc[5]));
    __half2 h3 = __float22half2_rn(make_float2(acc[6], acc[7]));
    uint4 u;
    u.x = *(const uint32_t*)&h0; u.y = *(const uint32_t*)&h1;
    u.z = *(const uint32_t*)&h2; u.w = *(const uint32_t*)&h3;
    ((uint4*)mirOut)[(size_t)row * 16 + l16] = u;
  }
}

// ---------------- Tier-2: f32 gather (no mirror) ----------------
__global__ __launch_bounds__(256) void gather_hop(const float* __restrict__ cur,
                                                  float* __restrict__ nxt,
                                                  const int* __restrict__ row_ptr,
                                                  const int* __restrict__ col,
                                                  int N, uint32_t fk0, uint32_t fk1) {
  long t = (long)blockIdx.x * blockDim.x + threadIdx.x;
  int row = (int)(t >> 6);
  if (row >= N) return;
  int lane = (int)(t & 63);
  int half = lane >> 5;
  int l32 = lane & 31;

  float4 acc = make_float4(0.f, 0.f, 0.f, 0.f);
  int beg = row_ptr[row], end = row_ptr[row + 1];
  int i = beg + half;
  for (; i + 6 < end; i += 8) {
    int s0 = col[i], s1 = col[i + 2], s2 = col[i + 4], s3 = col[i + 6];
    float4 v0 = ((const float4*)(cur + (size_t)s0 * D))[l32];
    float4 v1 = ((const float4*)(cur + (size_t)s1 * D))[l32];
    float4 v2 = ((const float4*)(cur + (size_t)s2 * D))[l32];
    float4 v3 = ((const float4*)(cur + (size_t)s3 * D))[l32];
    acc.x += v0.x + v1.x + v2.x + v3.x;
    acc.y += v0.y + v1.y + v2.y + v3.y;
    acc.z += v0.z + v1.z + v2.z + v3.z;
    acc.w += v0.w + v1.w + v2.w + v3.w;
  }
  for (; i < end; i += 2) {
    int s = col[i];
    float4 v = ((const float4*)(cur + (size_t)s * D))[l32];
    acc.x += v.x; acc.y += v.y; acc.z += v.z; acc.w += v.w;
  }
  acc.x += __shfl_xor(acc.x, 32, 64);
  acc.y += __shfl_xor(acc.y, 32, 64);
  acc.z += __shfl_xor(acc.z, 32, 64);
  acc.w += __shfl_xor(acc.w, 32, 64);

  long t0 = (long)row * D + l32 * 4;
  acc.x += noise_elem(fk0, fk1, t0);
  acc.y += noise_elem(fk0, fk1, t0 + 1);
  acc.z += noise_elem(fk0, fk1, t0 + 2);
  acc.w += noise_elem(fk0, fk1, t0 + 3);

  float ss = acc.x * acc.x + acc.y * acc.y + acc.z * acc.z + acc.w * acc.w;
  #pragma unroll
  for (int off = 16; off > 0; off >>= 1) ss += __shfl_xor(ss, off, 64);
  float inv = 1.0f / fmaxf(sqrtf(ss), 1e-12f);
  if (half == 0) {
    float4 o;
    o.x = acc.x * inv; o.y = acc.y * inv; o.z = acc.z * inv; o.w = acc.w * inv;
    ((float4*)(nxt + (size_t)row * D))[l32] = o;
  }
}

// ---------------- Tier-3 fallback kernels (atomic scatter) ----------------
__global__ __launch_bounds__(256) void noise_kernel(float* __restrict__ out,
                                                    uint32_t fk0, uint32_t fk1, long n) {
  long t = (long)blockIdx.x * blockDim.x + threadIdx.x;
  if (t >= n) return;
  out[t] = noise_elem(fk0, fk1, t);
}

__global__ __launch_bounds__(256) void scatter_kernel(const float* __restrict__ cur,
                                                      float* __restrict__ aggr,
                                                      const int* __restrict__ ei, long E) {
  long tid = (long)blockIdx.x * blockDim.x + threadIdx.x;
  long e = tid >> 5;
  if (e >= E) return;
  int lane = (int)(tid & 31);
  bool i64 = edges_are_i64(ei);
  int s = ei[i64 ? (2 * e) : e];
  int d = ei[i64 ? (2 * (E + e)) : (E + e)];
  float4 v = *(const float4*)(cur + (size_t)s * D + lane * 4);
  float* dp = aggr + (size_t)d * D + lane * 4;
  unsafeAtomicAdd(dp + 0, v.x);
  unsafeAtomicAdd(dp + 1, v.y);
  unsafeAtomicAdd(dp + 2, v.z);
  unsafeAtomicAdd(dp + 3, v.w);
}

__global__ __launch_bounds__(256) void norm_kernel(const float* __restrict__ in,
                                                   float* __restrict__ out, int N) {
  long t = (long)blockIdx.x * blockDim.x + threadIdx.x;
  int row = (int)(t >> 6);
  int lane = (int)(t & 63);
  if (row >= N) return;
  float2 v = *(const float2*)(in + (size_t)row * D + lane * 2);
  float s = v.x * v.x + v.y * v.y;
  #pragma unroll
  for (int off = 32; off > 0; off >>= 1) s += __shfl_xor(s, off, 64);
  float inv = 1.0f / fmaxf(sqrtf(s), 1e-12f);
  float2 o; o.x = v.x * inv; o.y = v.y * inv;
  *(float2*)(out + (size_t)row * D + lane * 2) = o;
}

extern "C" void kernel_launch(void* const* d_in, const int* in_sizes, int n_in,
                              void* d_out, int out_size, void* d_ws, size_t ws_size,
                              hipStream_t stream) {
  const float* x = (const float*)d_in[0];
  const int* ei = (const int*)d_in[1];
  const long N = in_sizes[0] / D;      // 100000
  const long E = in_sizes[1] / 2;     // 3200000
  float* out = (float*)d_out;
  const long ND = N * D;

  uint32_t fk0[NUM_HOPS], fk1[NUM_HOPS];
  for (int k = 0; k < NUM_HOPS; ++k)
    tf2x32(0u, 42u, 0u, (uint32_t)k, &fk0[k], &fk1[k]);

  // Workspace: row_ptr[N+1] | counts[N] | partials[nchunks] | col[E] | mirA | mirB
  const int nchunks = (int)((N + SCAN_BS - 1) / SCAN_BS);
  size_t csr_ints = (size_t)(N + 1) + (size_t)N + (size_t)nchunks + (size_t)E;
  csr_ints = (csr_ints + 7) & ~(size_t)7;                 // 32B-align mirrors
  size_t need_csr  = csr_ints * sizeof(int);
  size_t need_full = need_csr + 2 * (size_t)ND * sizeof(__half);

  if (ws_size >= need_csr && nchunks <= SCAN2_BS) {
    int* row_ptr  = (int*)d_ws;
    int* counts   = row_ptr + (N + 1);
    int* partials = counts + N;
    int* col      = partials + nchunks;

    hipMemsetAsync(counts, 0, (size_t)N * sizeof(int), stream);
    hist_kernel<<<(int)((E + 255) / 256), 256, 0, stream>>>(ei, counts, E);
    scan1_kernel<<<nchunks, SCAN_BS, 0, stream>>>(counts, row_ptr, partials, (int)N);
    scan2_kernel<<<1, SCAN2_BS, 0, stream>>>(partials, nchunks);
    scan3_kernel<<<(int)((N + 256) / 256), 256, 0, stream>>>(row_ptr, partials, counts, (int)N, (int)E);
    fill_kernel<<<(int)((E + 255) / 256), 256, 0, stream>>>(ei, counts, col, E);

    long nthreads = N * 64;
    int ngrid = (int)((nthreads + 255) / 256);

    if (ws_size >= need_full) {
      __half* mirA = (__half*)((char*)d_ws + need_csr);
      __half* mirB = mirA + ND;
      norm0_kernel<<<ngrid, 256, 0, stream>>>(x, out, mirA, (int)N);
      for (int k = 0; k < NUM_HOPS; ++k) {
        float* nxt = out + (size_t)(k + 1) * ND;
        const __half* mi = (k & 1) ? mirB : mirA;
        __half* mo       = (k & 1) ? mirA : mirB;
        gather_hop_f16<<<ngrid, 256, 0, stream>>>(mi, nxt, mo, row_ptr, col,
                                                  (int)N, fk0[k], fk1[k]);
      }
    } else {
      norm_kernel<<<ngrid, 256, 0, stream>>>(x, out, (int)N);
      for (int k = 0; k < NUM_HOPS; ++k) {
        const float* cur = out + (size_t)k * ND;
        float* nxt = out + (size_t)(k + 1) * ND;
        gather_hop<<<ngrid, 256, 0, stream>>>(cur, nxt, row_ptr, col, (int)N, fk0[k], fk1[k]);
      }
    }
  } else {
    long nthreads = N * 64;
    norm_kernel<<<(int)((nthreads + 255) / 256), 256, 0, stream>>>(x, out, (int)N);
    for (int k = 0; k < NUM_HOPS; ++k) {
      const float* cur = out + (size_t)k * ND;
      float* nxt = out + (size_t)(k + 1) * ND;
      noise_kernel<<<(int)((ND + 255) / 256), 256, 0, stream>>>(nxt, fk0[k], fk1[k], ND);
      long sthreads = E * 32;
      scatter_kernel<<<(int)((sthreads + 255) / 256), 256, 0, stream>>>(cur, nxt, ei, E);
      norm_kernel<<<(int)((nthreads + 255) / 256), 256, 0, stream>>>(nxt, nxt, (int)N);
    }
  }
}

// Round 8
// 1197.742 us; speedup vs baseline: 1.8746x; 1.3222x over previous
//
#include <hip/hip_runtime.h>
#include <hip/hip_bf16.h>
#include <hip/hip_fp16.h>
#include <stdint.h>

#define D 128
#define NUM_HOPS 8
#define SCAN_BS 256
#define SCAN2_BS 512
#define FILLA_EPT 16   // edges per thread in fillA (4096/wg)

// ---------------- Threefry-2x32 (matches jax._src.prng) ----------------
__host__ __device__ inline void tf2x32(uint32_t k0, uint32_t k1,
                                       uint32_t x0, uint32_t x1,
                                       uint32_t* o0, uint32_t* o1) {
  uint32_t ks2 = k0 ^ k1 ^ 0x1BD11BDAu;
  x0 += k0; x1 += k1;
#define TF_RND(r) { x0 += x1; x1 = (x1 << r) | (x1 >> (32 - r)); x1 ^= x0; }
  TF_RND(13) TF_RND(15) TF_RND(26) TF_RND(6)
  x0 += k1; x1 += ks2 + 1u;
  TF_RND(17) TF_RND(29) TF_RND(16) TF_RND(24)
  x0 += ks2; x1 += k0 + 2u;
  TF_RND(13) TF_RND(15) TF_RND(26) TF_RND(6)
  x0 += k0; x1 += k1 + 3u;
  TF_RND(17) TF_RND(29) TF_RND(16) TF_RND(24)
  x0 += k1; x1 += ks2 + 4u;
  TF_RND(13) TF_RND(15) TF_RND(26) TF_RND(6)
  x0 += ks2; x1 += k0 + 5u;
#undef TF_RND
  *o0 = x0; *o1 = x1;
}

// XLA ErfInv32 (Giles polynomial, w = -log1p(-x*x))
__device__ inline float erfinv_f32(float x) {
  float w = -log1pf(-x * x);
  float p;
  if (w < 5.0f) {
    w = w - 2.5f;
    p = 2.81022636e-08f;
    p = fmaf(p, w, 3.43273939e-07f);
    p = fmaf(p, w, -3.5233877e-06f);
    p = fmaf(p, w, -4.39150654e-06f);
    p = fmaf(p, w, 0.00021858087f);
    p = fmaf(p, w, -0.00125372503f);
    p = fmaf(p, w, -0.00417768164f);
    p = fmaf(p, w, 0.246640727f);
    p = fmaf(p, w, 1.50140941f);
  } else {
    w = sqrtf(w) - 3.0f;
    p = -0.000200214257f;
    p = fmaf(p, w, 0.000100950558f);
    p = fmaf(p, w, 0.00134934322f);
    p = fmaf(p, w, -0.00367342844f);
    p = fmaf(p, w, 0.00573950773f);
    p = fmaf(p, w, -0.0076224613f);
    p = fmaf(p, w, 0.00943887047f);
    p = fmaf(p, w, 1.00167406f);
    p = fmaf(p, w, 2.83297682f);
  }
  return p * x;
}

__device__ inline float noise_from_bits(uint32_t bits) {
  const float lo = -0.99999994f;            // nextafter(-1,0) in f32
  uint32_t fb = (bits >> 9) | 0x3f800000u;
  float f = __uint_as_float(fb) - 1.0f;     // [0,1)
  float u = fmaxf(lo, fmaf(f, 2.0f, lo));   // hi-lo rounds to exactly 2.0f
  return 0.1f * (1.41421354f * erfinv_f32(u));
}

__device__ inline float noise_elem(uint32_t fk0, uint32_t fk1, long t) {
  uint32_t o0, o1;
  tf2x32(fk0, fk1, (uint32_t)(((unsigned long)t) >> 32), (uint32_t)t, &o0, &o1);
  return noise_from_bits(o0 ^ o1);
}

// Detect int64 edge_index passed raw (odd int32 slots all-zero high words).
__device__ inline bool edges_are_i64(const int* __restrict__ ei) {
  return (ei[1] | ei[3] | ei[5] | ei[7] | ei[9] | ei[11] | ei[13] | ei[15]) == 0;
}

// ---------------- CSR build ----------------
__global__ __launch_bounds__(256) void hist_kernel(const int* __restrict__ ei,
                                                   int* __restrict__ counts, long E) {
  long e = (long)blockIdx.x * blockDim.x + threadIdx.x;
  if (e >= E) return;
  bool i64 = edges_are_i64(ei);
  int d = __builtin_nontemporal_load(&ei[i64 ? (2 * (E + e)) : (E + e)]);
  atomicAdd(&counts[d], 1);
}

__global__ __launch_bounds__(SCAN_BS) void scan1_kernel(const int* __restrict__ counts,
                                                        int* __restrict__ excl,
                                                        int* __restrict__ partials, int N) {
  __shared__ int lds[SCAN_BS];
  int tid = threadIdx.x;
  int i = blockIdx.x * SCAN_BS + tid;
  int v = (i < N) ? counts[i] : 0;
  lds[tid] = v;
  __syncthreads();
  for (int off = 1; off < SCAN_BS; off <<= 1) {
    int t = (tid >= off) ? lds[tid - off] : 0;
    __syncthreads();
    if (tid >= off) lds[tid] += t;
    __syncthreads();
  }
  int incl = lds[tid];
  if (i < N) excl[i] = incl - v;
  if (tid == SCAN_BS - 1) partials[blockIdx.x] = incl;
}

__global__ __launch_bounds__(SCAN2_BS) void scan2_kernel(int* __restrict__ partials, int nchunks) {
  __shared__ int lds[SCAN2_BS];
  int tid = threadIdx.x;
  int v = (tid < nchunks) ? partials[tid] : 0;
  lds[tid] = v;
  __syncthreads();
  for (int off = 1; off < SCAN2_BS; off <<= 1) {
    int t = (tid >= off) ? lds[tid - off] : 0;
    __syncthreads();
    if (tid >= off) lds[tid] += t;
    __syncthreads();
  }
  if (tid < nchunks) partials[tid] = lds[tid] - v;  // exclusive
}

__global__ __launch_bounds__(256) void scan3_kernel(int* __restrict__ row_ptr,
                                                    const int* __restrict__ partials,
                                                    int* __restrict__ cursor, int N, int E) {
  int i = blockIdx.x * blockDim.x + threadIdx.x;
  if (i > N) return;
  if (i == N) { row_ptr[N] = E; return; }
  int v = row_ptr[i] + partials[i >> 8];
  row_ptr[i] = v;
  cursor[i] = v;
}

// bucketCursor[b] = row_ptr[min(b<<shift, N)]
__global__ __launch_bounds__(256) void bucket_init_kernel(const int* __restrict__ row_ptr,
                                                          int* __restrict__ bucketCursor,
                                                          int nb, int shift, int N) {
  int b = blockIdx.x * blockDim.x + threadIdx.x;
  if (b >= nb) return;
  long r = (long)b << shift;
  if (r > N) r = N;
  bucketCursor[b] = row_ptr[r];
}

// fillA: bin (src,dst) into coarse buckets in tmp (packed u64: dst<<32|src).
// Per-wg LDS histogram -> one global atomic per (wg,bucket) -> contiguous runs.
__global__ __launch_bounds__(256) void fillA_kernel(const int* __restrict__ ei,
                                                    int* __restrict__ bucketCursor,
                                                    uint64_t* __restrict__ tmp,
                                                    long E, int shift, int nb) {
  __shared__ int ldsCount[256];
  __shared__ int ldsBase[256];
  __shared__ int ldsRank[256];
  int tid = threadIdx.x;
  long base = (long)blockIdx.x * (256 * FILLA_EPT);
  bool i64 = edges_are_i64(ei);

  int  sv[FILLA_EPT], dv[FILLA_EPT];
  ldsCount[tid] = 0; ldsRank[tid] = 0;
  __syncthreads();

  #pragma unroll
  for (int j = 0; j < FILLA_EPT; ++j) {
    long e = base + tid + (long)j * 256;
    if (e < E) {
      sv[j] = __builtin_nontemporal_load(&ei[i64 ? (2 * e) : e]);
      dv[j] = __builtin_nontemporal_load(&ei[i64 ? (2 * (E + e)) : (E + e)]);
      atomicAdd(&ldsCount[dv[j] >> shift], 1);
    } else { sv[j] = -1; dv[j] = -1; }
  }
  __syncthreads();
  if (tid < nb && ldsCount[tid] > 0)
    ldsBase[tid] = atomicAdd(&bucketCursor[tid], ldsCount[tid]);
  __syncthreads();
  #pragma unroll
  for (int j = 0; j < FILLA_EPT; ++j) {
    if (dv[j] >= 0) {
      int b = dv[j] >> shift;
      int r = atomicAdd(&ldsRank[b], 1);
      tmp[ldsBase[b] + r] = ((uint64_t)(uint32_t)dv[j] << 32) | (uint32_t)sv[j];
    }
  }
}

// fillB: one wg per bucket; scatter src into exact CSR slots. The bucket's
// col window (~64KB) is written by a single wg (single XCD L2).
__global__ __launch_bounds__(256) void fillB_kernel(const uint64_t* __restrict__ tmp,
                                                    const int* __restrict__ row_ptr,
                                                    int* __restrict__ cursor,
                                                    int* __restrict__ col,
                                                    int shift, int N) {
  int b = blockIdx.x;
  long r0 = (long)b << shift;
  long r1 = r0 + ((long)1 << shift);
  if (r0 > N) r0 = N;
  if (r1 > N) r1 = N;
  int beg = row_ptr[r0], end = row_ptr[r1];
  for (int i = beg + threadIdx.x; i < end; i += 256) {
    uint64_t e = __builtin_nontemporal_load(&tmp[i]);
    int d = (int)(e >> 32);
    int s = (int)(uint32_t)e;
    int slot = atomicAdd(&cursor[d], 1);
    col[slot] = s;
  }
}

// legacy single-pass fill (fallback when ws lacks tmp space)
__global__ __launch_bounds__(256) void fill_kernel(const int* __restrict__ ei,
                                                   int* __restrict__ cursor,
                                                   int* __restrict__ col, long E) {
  long e = (long)blockIdx.x * blockDim.x + threadIdx.x;
  if (e >= E) return;
  bool i64 = edges_are_i64(ei);
  int s = __builtin_nontemporal_load(&ei[i64 ? (2 * e) : e]);
  int d = __builtin_nontemporal_load(&ei[i64 ? (2 * (E + e)) : (E + e)]);
  int slot = atomicAdd(&cursor[d], 1);
  col[slot] = s;
}

// ---------------- hop 0: normalize x -> out[0] (f32) + mirror (f16) ----------------
__global__ __launch_bounds__(256) void norm0_kernel(const float* __restrict__ in,
                                                    float* __restrict__ out,
                                                    __half* __restrict__ mir, int N) {
  long t = (long)blockIdx.x * blockDim.x + threadIdx.x;
  int row = (int)(t >> 6);
  int lane = (int)(t & 63);
  if (row >= N) return;
  float2 v = *(const float2*)(in + (size_t)row * D + lane * 2);
  float s = v.x * v.x + v.y * v.y;
  #pragma unroll
  for (int off = 32; off > 0; off >>= 1) s += __shfl_xor(s, off, 64);
  float inv = 1.0f / fmaxf(sqrtf(s), 1e-12f);
  float2 o; o.x = v.x * inv; o.y = v.y * inv;
  *(float2*)(out + (size_t)row * D + lane * 2) = o;
  __half2 h = __float22half2_rn(o);
  ((uint32_t*)mir)[(size_t)row * 64 + lane] = *(const uint32_t*)&h;
}

// ---------------- Fused per-hop (f16 mirror): noise + gather + normalize ----------------
__global__ __launch_bounds__(256) void gather_hop_f16(const __half* __restrict__ mirIn,
                                                      float* __restrict__ nxt,
                                                      __half* __restrict__ mirOut,
                                                      const int* __restrict__ row_ptr,
                                                      const int* __restrict__ col,
                                                      int N, uint32_t fk0, uint32_t fk1) {
  long t = (long)blockIdx.x * blockDim.x + threadIdx.x;
  int row = (int)(t >> 6);
  if (row >= N) return;
  int lane = (int)(t & 63);
  int q = lane >> 4;
  int l16 = lane & 15;

  long t0 = (long)row * D + 2 * lane;
  float n0 = noise_elem(fk0, fk1, t0);
  float n1 = noise_elem(fk0, fk1, t0 + 1);

  float acc[8];
  #pragma unroll
  for (int j = 0; j < 8; ++j) acc[j] = 0.f;

  auto acc8 = [&](uint4 a) {
    const __half2* hp = (const __half2*)&a;
    #pragma unroll
    for (int j = 0; j < 4; ++j) {
      float2 f = __half22float2(hp[j]);
      acc[2 * j]     += f.x;
      acc[2 * j + 1] += f.y;
    }
  };

  const uint4* mir4 = (const uint4*)mirIn;   // 16 uint4 per 256B-aligned row
  int beg = row_ptr[row], end = row_ptr[row + 1];
  int i = beg + q;
  for (; i + 4 < end; i += 8) {
    int s0 = col[i];
    int s1 = col[i + 4];
    uint4 a = mir4[(size_t)s0 * 16 + l16];
    uint4 b = mir4[(size_t)s1 * 16 + l16];
    acc8(a); acc8(b);
  }
  for (; i < end; i += 4) {
    int s = col[i];
    acc8(mir4[(size_t)s * 16 + l16]);
  }

  #pragma unroll
  for (int j = 0; j < 8; ++j) {
    acc[j] += __shfl_xor(acc[j], 16, 64);
    acc[j] += __shfl_xor(acc[j], 32, 64);
  }

  #pragma unroll
  for (int j = 0; j < 8; ++j) {
    int src = (l16 << 2) | (j >> 1);
    acc[j] += __shfl((j & 1) ? n1 : n0, src, 64);
  }

  float ss = 0.f;
  #pragma unroll
  for (int j = 0; j < 8; ++j) ss += acc[j] * acc[j];
  ss += __shfl_xor(ss, 1, 64);
  ss += __shfl_xor(ss, 2, 64);
  ss += __shfl_xor(ss, 4, 64);
  ss += __shfl_xor(ss, 8, 64);
  float inv = 1.0f / fmaxf(sqrtf(ss), 1e-12f);
  #pragma unroll
  for (int j = 0; j < 8; ++j) acc[j] *= inv;

  if (q == 0) {
    float4* op = (float4*)(nxt + (size_t)row * D + l16 * 8);
    op[0] = make_float4(acc[0], acc[1], acc[2], acc[3]);
    op[1] = make_float4(acc[4], acc[5], acc[6], acc[7]);
  } else if (q == 1) {
    __half2 h0 = __float22half2_rn(make_float2(acc[0], acc[1]));
    __half2 h1 = __float22half2_rn(make_float2(acc[2], acc[3]));
    __half2 h2 = __float22half2_rn(make_float2(acc[4], acc[5]));
    __half2 h3 = __float22half2_rn(make_float2(acc[6], acc[7]));
    uint4 u;
    u.x = *(const uint32_t*)&h0; u.y = *(const uint32_t*)&h1;
    u.z = *(const uint32_t*)&h2; u.w = *(const uint32_t*)&h3;
    ((uint4*)mirOut)[(size_t)row * 16 + l16] = u;
  }
}

// ---------------- Tier-2: f32 gather (no mirror) ----------------
__global__ __launch_bounds__(256) void gather_hop(const float* __restrict__ cur,
                                                  float* __restrict__ nxt,
                                                  const int* __restrict__ row_ptr,
                                                  const int* __restrict__ col,
                                                  int N, uint32_t fk0, uint32_t fk1) {
  long t = (long)blockIdx.x * blockDim.x + threadIdx.x;
  int row = (int)(t >> 6);
  if (row >= N) return;
  int lane = (int)(t & 63);
  int half = lane >> 5;
  int l32 = lane & 31;

  float4 acc = make_float4(0.f, 0.f, 0.f, 0.f);
  int beg = row_ptr[row], end = row_ptr[row + 1];
  int i = beg + half;
  for (; i + 6 < end; i += 8) {
    int s0 = col[i], s1 = col[i + 2], s2 = col[i + 4], s3 = col[i + 6];
    float4 v0 = ((const float4*)(cur + (size_t)s0 * D))[l32];
    float4 v1 = ((const float4*)(cur + (size_t)s1 * D))[l32];
    float4 v2 = ((const float4*)(cur + (size_t)s2 * D))[l32];
    float4 v3 = ((const float4*)(cur + (size_t)s3 * D))[l32];
    acc.x += v0.x + v1.x + v2.x + v3.x;
    acc.y += v0.y + v1.y + v2.y + v3.y;
    acc.z += v0.z + v1.z + v2.z + v3.z;
    acc.w += v0.w + v1.w + v2.w + v3.w;
  }
  for (; i < end; i += 2) {
    int s = col[i];
    float4 v = ((const float4*)(cur + (size_t)s * D))[l32];
    acc.x += v.x; acc.y += v.y; acc.z += v.z; acc.w += v.w;
  }
  acc.x += __shfl_xor(acc.x, 32, 64);
  acc.y += __shfl_xor(acc.y, 32, 64);
  acc.z += __shfl_xor(acc.z, 32, 64);
  acc.w += __shfl_xor(acc.w, 32, 64);

  long t0 = (long)row * D + l32 * 4;
  acc.x += noise_elem(fk0, fk1, t0);
  acc.y += noise_elem(fk0, fk1, t0 + 1);
  acc.z += noise_elem(fk0, fk1, t0 + 2);
  acc.w += noise_elem(fk0, fk1, t0 + 3);

  float ss = acc.x * acc.x + acc.y * acc.y + acc.z * acc.z + acc.w * acc.w;
  #pragma unroll
  for (int off = 16; off > 0; off >>= 1) ss += __shfl_xor(ss, off, 64);
  float inv = 1.0f / fmaxf(sqrtf(ss), 1e-12f);
  if (half == 0) {
    float4 o;
    o.x = acc.x * inv; o.y = acc.y * inv; o.z = acc.z * inv; o.w = acc.w * inv;
    ((float4*)(nxt + (size_t)row * D))[l32] = o;
  }
}

// ---------------- Tier-3 fallback kernels (atomic scatter) ----------------
__global__ __launch_bounds__(256) void noise_kernel(float* __restrict__ out,
                                                    uint32_t fk0, uint32_t fk1, long n) {
  long t = (long)blockIdx.x * blockDim.x + threadIdx.x;
  if (t >= n) return;
  out[t] = noise_elem(fk0, fk1, t);
}

__global__ __launch_bounds__(256) void scatter_kernel(const float* __restrict__ cur,
                                                      float* __restrict__ aggr,
                                                      const int* __restrict__ ei, long E) {
  long tid = (long)blockIdx.x * blockDim.x + threadIdx.x;
  long e = tid >> 5;
  if (e >= E) return;
  int lane = (int)(tid & 31);
  bool i64 = edges_are_i64(ei);
  int s = ei[i64 ? (2 * e) : e];
  int d = ei[i64 ? (2 * (E + e)) : (E + e)];
  float4 v = *(const float4*)(cur + (size_t)s * D + lane * 4);
  float* dp = aggr + (size_t)d * D + lane * 4;
  unsafeAtomicAdd(dp + 0, v.x);
  unsafeAtomicAdd(dp + 1, v.y);
  unsafeAtomicAdd(dp + 2, v.z);
  unsafeAtomicAdd(dp + 3, v.w);
}

__global__ __launch_bounds__(256) void norm_kernel(const float* __restrict__ in,
                                                   float* __restrict__ out, int N) {
  long t = (long)blockIdx.x * blockDim.x + threadIdx.x;
  int row = (int)(t >> 6);
  int lane = (int)(t & 63);
  if (row >= N) return;
  float2 v = *(const float2*)(in + (size_t)row * D + lane * 2);
  float s = v.x * v.x + v.y * v.y;
  #pragma unroll
  for (int off = 32; off > 0; off >>= 1) s += __shfl_xor(s, off, 64);
  float inv = 1.0f / fmaxf(sqrtf(s), 1e-12f);
  float2 o; o.x = v.x * inv; o.y = v.y * inv;
  *(float2*)(out + (size_t)row * D + lane * 2) = o;
}

static inline size_t align_up(size_t v, size_t a) { return (v + a - 1) & ~(a - 1); }

extern "C" void kernel_launch(void* const* d_in, const int* in_sizes, int n_in,
                              void* d_out, int out_size, void* d_ws, size_t ws_size,
                              hipStream_t stream) {
  const float* x = (const float*)d_in[0];
  const int* ei = (const int*)d_in[1];
  const long N = in_sizes[0] / D;      // 100000
  const long E = in_sizes[1] / 2;      // 3200000
  float* out = (float*)d_out;
  const long ND = N * D;

  uint32_t fk0[NUM_HOPS], fk1[NUM_HOPS];
  for (int k = 0; k < NUM_HOPS; ++k)
    tf2x32(0u, 42u, 0u, (uint32_t)k, &fk0[k], &fk1[k]);

  // bucket shift: rows/bucket = 1<<shift, NB <= 256
  int shift = 9;
  while ((((N + ((long)1 << shift) - 1) >> shift)) > 256) shift++;
  const int nb = (int)((N + ((long)1 << shift) - 1) >> shift);
  const int nchunks = (int)((N + SCAN_BS - 1) / SCAN_BS);

  // Aligned workspace carve-out (all big arrays 256B-aligned)
  uintptr_t base = (uintptr_t)d_ws;
  size_t off = 0;
  auto carve = [&](size_t bytes, size_t align) -> uintptr_t {
    off = align_up(off, align);
    uintptr_t p = base + off;
    off += bytes;
    return p;
  };
  int* row_ptr      = (int*)carve((size_t)(N + 1) * 4, 256);
  int* counts       = (int*)carve((size_t)N * 4, 256);
  int* partials     = (int*)carve((size_t)nchunks * 4, 256);
  int* bucketCursor = (int*)carve((size_t)nb * 4, 256);
  int* col          = (int*)carve((size_t)E * 4, 256);
  size_t need_csr = off;
  uint64_t* tmp     = (uint64_t*)carve((size_t)E * 8, 256);
  size_t need_tmp = off;
  __half* mirA      = (__half*)carve((size_t)ND * 2, 256);
  __half* mirB      = (__half*)carve((size_t)ND * 2, 256);
  size_t need_full = off;

  long nthreads = N * 64;
  int ngrid = (int)((nthreads + 255) / 256);

  if (ws_size >= need_csr && nchunks <= SCAN2_BS) {
    (void)hipMemsetAsync(counts, 0, (size_t)N * sizeof(int), stream);
    hist_kernel<<<(int)((E + 255) / 256), 256, 0, stream>>>(ei, counts, E);
    scan1_kernel<<<nchunks, SCAN_BS, 0, stream>>>(counts, row_ptr, partials, (int)N);
    scan2_kernel<<<1, SCAN2_BS, 0, stream>>>(partials, nchunks);
    scan3_kernel<<<(int)((N + 256) / 256), 256, 0, stream>>>(row_ptr, partials, counts, (int)N, (int)E);

    bool have_tmp = (ws_size >= need_tmp);
    if (have_tmp) {
      bucket_init_kernel<<<(nb + 255) / 256, 256, 0, stream>>>(row_ptr, bucketCursor, nb, shift, (int)N);
      long epw = 256L * FILLA_EPT;
      fillA_kernel<<<(int)((E + epw - 1) / epw), 256, 0, stream>>>(ei, bucketCursor, tmp, E, shift, nb);
      fillB_kernel<<<nb, 256, 0, stream>>>(tmp, row_ptr, counts, col, shift, (int)N);
    } else {
      fill_kernel<<<(int)((E + 255) / 256), 256, 0, stream>>>(ei, counts, col, E);
    }

    if (ws_size >= need_full) {
      norm0_kernel<<<ngrid, 256, 0, stream>>>(x, out, mirA, (int)N);
      for (int k = 0; k < NUM_HOPS; ++k) {
        float* nxt = out + (size_t)(k + 1) * ND;
        const __half* mi = (k & 1) ? mirB : mirA;
        __half* mo       = (k & 1) ? mirA : mirB;
        gather_hop_f16<<<ngrid, 256, 0, stream>>>(mi, nxt, mo, row_ptr, col,
                                                  (int)N, fk0[k], fk1[k]);
      }
    } else if (!have_tmp && ws_size >= need_csr + 2 * (size_t)ND * sizeof(__half) + 512) {
      // mirrors fit where tmp would have gone
      __half* mA = (__half*)((char*)align_up((size_t)((char*)d_ws - (char*)0) + need_csr, 256));
      mA = (__half*)((char*)d_ws + (align_up(need_csr, 256) - 0));
      __half* mB = mA + ND;
      norm0_kernel<<<ngrid, 256, 0, stream>>>(x, out, mA, (int)N);
      for (int k = 0; k < NUM_HOPS; ++k) {
        float* nxt = out + (size_t)(k + 1) * ND;
        const __half* mi = (k & 1) ? mB : mA;
        __half* mo       = (k & 1) ? mA : mB;
        gather_hop_f16<<<ngrid, 256, 0, stream>>>(mi, nxt, mo, row_ptr, col,
                                                  (int)N, fk0[k], fk1[k]);
      }
    } else {
      norm_kernel<<<ngrid, 256, 0, stream>>>(x, out, (int)N);
      for (int k = 0; k < NUM_HOPS; ++k) {
        const float* cur = out + (size_t)k * ND;
        float* nxt = out + (size_t)(k + 1) * ND;
        gather_hop<<<ngrid, 256, 0, stream>>>(cur, nxt, row_ptr, col, (int)N, fk0[k], fk1[k]);
      }
    }
  } else {
    norm_kernel<<<ngrid, 256, 0, stream>>>(x, out, (int)N);
    for (int k = 0; k < NUM_HOPS; ++k) {
      const float* cur = out + (size_t)k * ND;
      float* nxt = out + (size_t)(k + 1) * ND;
      noise_kernel<<<(int)((ND + 255) / 256), 256, 0, stream>>>(nxt, fk0[k], fk1[k], ND);
      long sthreads = E * 32;
      scatter_kernel<<<(int)((sthreads + 255) / 256), 256, 0, stream>>>(cur, nxt, ei, E);
      norm_kernel<<<ngrid, 256, 0, stream>>>(nxt, nxt, (int)N);
    }
  }
}

// Round 9
// 1137.381 us; speedup vs baseline: 1.9741x; 1.0531x over previous
//
#include <hip/hip_runtime.h>
#include <hip/hip_fp16.h>
#include <stdint.h>

#define D 128
#define NUM_HOPS 8
#define FILLA_EPT 16   // edges per thread in binning kernels (4096/wg)

typedef float f32x2 __attribute__((ext_vector_type(2)));
typedef float f32x4 __attribute__((ext_vector_type(4)));
typedef unsigned int u32x4 __attribute__((ext_vector_type(4)));

// ---------------- Threefry-2x32 (matches jax._src.prng) ----------------
__host__ __device__ inline void tf2x32(uint32_t k0, uint32_t k1,
                                       uint32_t x0, uint32_t x1,
                                       uint32_t* o0, uint32_t* o1) {
  uint32_t ks2 = k0 ^ k1 ^ 0x1BD11BDAu;
  x0 += k0; x1 += k1;
#define TF_RND(r) { x0 += x1; x1 = (x1 << r) | (x1 >> (32 - r)); x1 ^= x0; }
  TF_RND(13) TF_RND(15) TF_RND(26) TF_RND(6)
  x0 += k1; x1 += ks2 + 1u;
  TF_RND(17) TF_RND(29) TF_RND(16) TF_RND(24)
  x0 += ks2; x1 += k0 + 2u;
  TF_RND(13) TF_RND(15) TF_RND(26) TF_RND(6)
  x0 += k0; x1 += k1 + 3u;
  TF_RND(17) TF_RND(29) TF_RND(16) TF_RND(24)
  x0 += k1; x1 += ks2 + 4u;
  TF_RND(13) TF_RND(15) TF_RND(26) TF_RND(6)
  x0 += ks2; x1 += k0 + 5u;
#undef TF_RND
  *o0 = x0; *o1 = x1;
}

// XLA ErfInv32 (Giles polynomial, w = -log1p(-x*x))
__device__ inline float erfinv_f32(float x) {
  float w = -log1pf(-x * x);
  float p;
  if (w < 5.0f) {
    w = w - 2.5f;
    p = 2.81022636e-08f;
    p = fmaf(p, w, 3.43273939e-07f);
    p = fmaf(p, w, -3.5233877e-06f);
    p = fmaf(p, w, -4.39150654e-06f);
    p = fmaf(p, w, 0.00021858087f);
    p = fmaf(p, w, -0.00125372503f);
    p = fmaf(p, w, -0.00417768164f);
    p = fmaf(p, w, 0.246640727f);
    p = fmaf(p, w, 1.50140941f);
  } else {
    w = sqrtf(w) - 3.0f;
    p = -0.000200214257f;
    p = fmaf(p, w, 0.000100950558f);
    p = fmaf(p, w, 0.00134934322f);
    p = fmaf(p, w, -0.00367342844f);
    p = fmaf(p, w, 0.00573950773f);
    p = fmaf(p, w, -0.0076224613f);
    p = fmaf(p, w, 0.00943887047f);
    p = fmaf(p, w, 1.00167406f);
    p = fmaf(p, w, 2.83297682f);
  }
  return p * x;
}

__device__ inline float noise_from_bits(uint32_t bits) {
  const float lo = -0.99999994f;            // nextafter(-1,0) in f32
  uint32_t fb = (bits >> 9) | 0x3f800000u;
  float f = __uint_as_float(fb) - 1.0f;     // [0,1)
  float u = fmaxf(lo, fmaf(f, 2.0f, lo));   // hi-lo rounds to exactly 2.0f
  return 0.1f * (1.41421354f * erfinv_f32(u));
}

__device__ inline float noise_elem(uint32_t fk0, uint32_t fk1, long t) {
  uint32_t o0, o1;
  tf2x32(fk0, fk1, (uint32_t)(((unsigned long)t) >> 32), (uint32_t)t, &o0, &o1);
  return noise_from_bits(o0 ^ o1);
}

// Detect int64 edge_index passed raw (odd int32 slots all-zero high words).
__device__ inline bool edges_are_i64(const int* __restrict__ ei) {
  return (ei[1] | ei[3] | ei[5] | ei[7] | ei[9] | ei[11] | ei[13] | ei[15]) == 0;
}

// ---------------- CSR build (bucketed, no global histogram) ----------------
__global__ __launch_bounds__(256) void zero256_kernel(int* __restrict__ p) {
  p[threadIdx.x] = 0;
}

// LDS-staged coarse histogram: 256 global atomics per wg instead of E.
__global__ __launch_bounds__(256) void bucket_hist_kernel(const int* __restrict__ ei,
                                                          int* __restrict__ bucketCount,
                                                          long E, int shift) {
  __shared__ int cnt[256];
  int tid = threadIdx.x;
  cnt[tid] = 0;
  __syncthreads();
  long base = (long)blockIdx.x * (256 * FILLA_EPT);
  bool i64 = edges_are_i64(ei);
  #pragma unroll
  for (int j = 0; j < FILLA_EPT; ++j) {
    long e = base + tid + (long)j * 256;
    if (e < E) {
      int d = __builtin_nontemporal_load(&ei[i64 ? (2 * (E + e)) : (E + e)]);
      atomicAdd(&cnt[d >> shift], 1);
    }
  }
  __syncthreads();
  if (cnt[tid] > 0) atomicAdd(&bucketCount[tid], cnt[tid]);
}

// single-wg exclusive scan of bucket counts -> bases + cursors
__global__ __launch_bounds__(256) void bucket_scan_kernel(const int* __restrict__ bucketCount,
                                                          int* __restrict__ bucketBase,
                                                          int* __restrict__ bucketCursor,
                                                          int nb, int E) {
  __shared__ int lds[256];
  int tid = threadIdx.x;
  int v = (tid < nb) ? bucketCount[tid] : 0;
  lds[tid] = v;
  __syncthreads();
  for (int off = 1; off < 256; off <<= 1) {
    int t = (tid >= off) ? lds[tid - off] : 0;
    __syncthreads();
    lds[tid] += t;
    __syncthreads();
  }
  int excl = lds[tid] - v;
  if (tid < nb) { bucketBase[tid] = excl; bucketCursor[tid] = excl; }
  if (tid == 0) bucketBase[nb] = E;
}

// fillA: bin (src,dst) into coarse buckets in tmp (packed u64: dst<<32|src).
// Per-wg LDS histogram -> one global atomic per (wg,bucket) -> contiguous runs.
__global__ __launch_bounds__(256) void fillA_kernel(const int* __restrict__ ei,
                                                    int* __restrict__ bucketCursor,
                                                    uint64_t* __restrict__ tmp,
                                                    long E, int shift, int nb) {
  __shared__ int ldsCount[256];
  __shared__ int ldsBase[256];
  __shared__ int ldsRank[256];
  int tid = threadIdx.x;
  long base = (long)blockIdx.x * (256 * FILLA_EPT);
  bool i64 = edges_are_i64(ei);

  int sv[FILLA_EPT], dv[FILLA_EPT];
  ldsCount[tid] = 0; ldsRank[tid] = 0;
  __syncthreads();

  #pragma unroll
  for (int j = 0; j < FILLA_EPT; ++j) {
    long e = base + tid + (long)j * 256;
    if (e < E) {
      sv[j] = __builtin_nontemporal_load(&ei[i64 ? (2 * e) : e]);
      dv[j] = __builtin_nontemporal_load(&ei[i64 ? (2 * (E + e)) : (E + e)]);
      atomicAdd(&ldsCount[dv[j] >> shift], 1);
    } else { sv[j] = -1; dv[j] = -1; }
  }
  __syncthreads();
  if (tid < nb && ldsCount[tid] > 0)
    ldsBase[tid] = atomicAdd(&bucketCursor[tid], ldsCount[tid]);
  __syncthreads();
  #pragma unroll
  for (int j = 0; j < FILLA_EPT; ++j) {
    if (dv[j] >= 0) {
      int b = dv[j] >> shift;
      int r = atomicAdd(&ldsRank[b], 1);
      tmp[ldsBase[b] + r] = ((uint64_t)(uint32_t)dv[j] << 32) | (uint32_t)sv[j];
    }
  }
}

// fillB2: one wg per bucket. Bucket-local histogram + scan + cursors in LDS;
// writes row_ptr for its rows and scatters col within its window — no global
// cursor atomics, no global scan kernels.
__global__ __launch_bounds__(256) void fillB2_kernel(const uint64_t* __restrict__ tmp,
                                                     const int* __restrict__ bucketBase,
                                                     int* __restrict__ row_ptr,
                                                     int* __restrict__ col,
                                                     int shift, int N, int nb) {
  __shared__ int h[512];    // counts, then reused as cursors
  __shared__ int ex[512];   // exclusive prefix per local row
  __shared__ int ps[256];   // pair sums for scan
  int b = blockIdx.x;
  int tid = threadIdx.x;
  int r0 = b << shift;
  int bs = 1 << shift;                 // <= 512 guaranteed by host
  int rows = N - r0; if (rows > bs) rows = bs;
  int beg = bucketBase[b], end = bucketBase[b + 1];

  h[tid] = 0; h[tid + 256] = 0;
  __syncthreads();
  for (int i = beg + tid; i < end; i += 256) {
    uint64_t e = __builtin_nontemporal_load(&tmp[i]);
    int r = (int)(e >> 32) - r0;
    atomicAdd(&h[r], 1);
  }
  __syncthreads();
  int a = h[2 * tid], c = h[2 * tid + 1];
  ps[tid] = a + c;
  __syncthreads();
  for (int off = 1; off < 256; off <<= 1) {
    int t = (tid >= off) ? ps[tid - off] : 0;
    __syncthreads();
    ps[tid] += t;
    __syncthreads();
  }
  int pe = ps[tid] - (a + c);          // exclusive pair base
  ex[2 * tid] = pe;
  ex[2 * tid + 1] = pe + a;
  __syncthreads();
  for (int r = tid; r < bs; r += 256) {
    if (r < rows) row_ptr[r0 + r] = beg + ex[r];
    h[r] = ex[r];                      // cursor init
  }
  if (b == nb - 1 && tid == 0) row_ptr[N] = end;
  __syncthreads();
  for (int i = beg + tid; i < end; i += 256) {
    uint64_t e = __builtin_nontemporal_load(&tmp[i]);
    int r = (int)(e >> 32) - r0;
    int slot = beg + atomicAdd(&h[r], 1);
    col[slot] = (int)(uint32_t)e;
  }
}

// ---------------- hop 0: normalize x -> out[0] (f32, NT) + mirror (f16) ----------------
__global__ __launch_bounds__(256) void norm0_kernel(const float* __restrict__ in,
                                                    float* __restrict__ out,
                                                    __half* __restrict__ mir, int N) {
  long t = (long)blockIdx.x * blockDim.x + threadIdx.x;
  int row = (int)(t >> 6);
  int lane = (int)(t & 63);
  if (row >= N) return;
  float2 v = *(const float2*)(in + (size_t)row * D + lane * 2);
  float s = v.x * v.x + v.y * v.y;
  #pragma unroll
  for (int off = 32; off > 0; off >>= 1) s += __shfl_xor(s, off, 64);
  float inv = 1.0f / fmaxf(sqrtf(s), 1e-12f);
  f32x2 o; o.x = v.x * inv; o.y = v.y * inv;
  __builtin_nontemporal_store(o, (f32x2*)(out + (size_t)row * D + lane * 2));
  __half2 h = __float22half2_rn(make_float2(o.x, o.y));
  ((uint32_t*)mir)[(size_t)row * 64 + lane] = *(const uint32_t*)&h;
}

// ---------------- Fused per-hop (f16 mirror): noise + gather + normalize ----------------
__global__ __launch_bounds__(256) void gather_hop_f16(const __half* __restrict__ mirIn,
                                                      float* __restrict__ nxt,
                                                      __half* __restrict__ mirOut,
                                                      const int* __restrict__ row_ptr,
                                                      const int* __restrict__ col,
                                                      int N, uint32_t fk0, uint32_t fk1) {
  long t = (long)blockIdx.x * blockDim.x + threadIdx.x;
  int row = (int)(t >> 6);
  if (row >= N) return;
  int lane = (int)(t & 63);
  int q = lane >> 4;
  int l16 = lane & 15;

  long t0 = (long)row * D + 2 * lane;
  float n0 = noise_elem(fk0, fk1, t0);
  float n1 = noise_elem(fk0, fk1, t0 + 1);

  float acc[8];
  #pragma unroll
  for (int j = 0; j < 8; ++j) acc[j] = 0.f;

  auto acc8 = [&](uint4 a) {
    const __half2* hp = (const __half2*)&a;
    #pragma unroll
    for (int j = 0; j < 4; ++j) {
      float2 f = __half22float2(hp[j]);
      acc[2 * j]     += f.x;
      acc[2 * j + 1] += f.y;
    }
  };

  const uint4* mir4 = (const uint4*)mirIn;   // 16 uint4 per 256B-aligned row
  int beg = row_ptr[row], end = row_ptr[row + 1];
  int i = beg + q;
  for (; i + 4 < end; i += 8) {
    int s0 = __builtin_nontemporal_load(&col[i]);
    int s1 = __builtin_nontemporal_load(&col[i + 4]);
    uint4 a = mir4[(size_t)s0 * 16 + l16];
    uint4 b = mir4[(size_t)s1 * 16 + l16];
    acc8(a); acc8(b);
  }
  for (; i < end; i += 4) {
    int s = __builtin_nontemporal_load(&col[i]);
    acc8(mir4[(size_t)s * 16 + l16]);
  }

  #pragma unroll
  for (int j = 0; j < 8; ++j) {
    acc[j] += __shfl_xor(acc[j], 16, 64);
    acc[j] += __shfl_xor(acc[j], 32, 64);
  }

  #pragma unroll
  for (int j = 0; j < 8; ++j) {
    int src = (l16 << 2) | (j >> 1);
    acc[j] += __shfl((j & 1) ? n1 : n0, src, 64);
  }

  float ss = 0.f;
  #pragma unroll
  for (int j = 0; j < 8; ++j) ss += acc[j] * acc[j];
  ss += __shfl_xor(ss, 1, 64);
  ss += __shfl_xor(ss, 2, 64);
  ss += __shfl_xor(ss, 4, 64);
  ss += __shfl_xor(ss, 8, 64);
  float inv = 1.0f / fmaxf(sqrtf(ss), 1e-12f);
  #pragma unroll
  for (int j = 0; j < 8; ++j) acc[j] *= inv;

  if (q == 0) {                              // f32 output row, NT (never re-read)
    f32x4 o0 = {acc[0], acc[1], acc[2], acc[3]};
    f32x4 o1 = {acc[4], acc[5], acc[6], acc[7]};
    f32x4* op = (f32x4*)(nxt + (size_t)row * D + l16 * 8);
    __builtin_nontemporal_store(o0, op);
    __builtin_nontemporal_store(o1, op + 1);
  } else if (q == 1) {                       // f16 mirror row, NT (self-evicting)
    __half2 h0 = __float22half2_rn(make_float2(acc[0], acc[1]));
    __half2 h1 = __float22half2_rn(make_float2(acc[2], acc[3]));
    __half2 h2 = __float22half2_rn(make_float2(acc[4], acc[5]));
    __half2 h3 = __float22half2_rn(make_float2(acc[6], acc[7]));
    u32x4 u = { *(const uint32_t*)&h0, *(const uint32_t*)&h1,
                *(const uint32_t*)&h2, *(const uint32_t*)&h3 };
    __builtin_nontemporal_store(u, (u32x4*)mirOut + ((size_t)row * 16 + l16));
  }
}

// ---------------- Fallback kernels (round-3 atomic path, proven) ----------------
__global__ __launch_bounds__(256) void noise_kernel(float* __restrict__ out,
                                                    uint32_t fk0, uint32_t fk1, long n) {
  long t = (long)blockIdx.x * blockDim.x + threadIdx.x;
  if (t >= n) return;
  out[t] = noise_elem(fk0, fk1, t);
}

__global__ __launch_bounds__(256) void scatter_kernel(const float* __restrict__ cur,
                                                      float* __restrict__ aggr,
                                                      const int* __restrict__ ei, long E) {
  long tid = (long)blockIdx.x * blockDim.x + threadIdx.x;
  long e = tid >> 5;
  if (e >= E) return;
  int lane = (int)(tid & 31);
  bool i64 = edges_are_i64(ei);
  int s = ei[i64 ? (2 * e) : e];
  int d = ei[i64 ? (2 * (E + e)) : (E + e)];
  float4 v = *(const float4*)(cur + (size_t)s * D + lane * 4);
  float* dp = aggr + (size_t)d * D + lane * 4;
  unsafeAtomicAdd(dp + 0, v.x);
  unsafeAtomicAdd(dp + 1, v.y);
  unsafeAtomicAdd(dp + 2, v.z);
  unsafeAtomicAdd(dp + 3, v.w);
}

__global__ __launch_bounds__(256) void norm_kernel(const float* __restrict__ in,
                                                   float* __restrict__ out, int N) {
  long t = (long)blockIdx.x * blockDim.x + threadIdx.x;
  int row = (int)(t >> 6);
  int lane = (int)(t & 63);
  if (row >= N) return;
  float2 v = *(const float2*)(in + (size_t)row * D + lane * 2);
  float s = v.x * v.x + v.y * v.y;
  #pragma unroll
  for (int off = 32; off > 0; off >>= 1) s += __shfl_xor(s, off, 64);
  float inv = 1.0f / fmaxf(sqrtf(s), 1e-12f);
  float2 o; o.x = v.x * inv; o.y = v.y * inv;
  *(float2*)(out + (size_t)row * D + lane * 2) = o;
}

static inline size_t align_up(size_t v, size_t a) { return (v + a - 1) & ~(a - 1); }

extern "C" void kernel_launch(void* const* d_in, const int* in_sizes, int n_in,
                              void* d_out, int out_size, void* d_ws, size_t ws_size,
                              hipStream_t stream) {
  const float* x = (const float*)d_in[0];
  const int* ei = (const int*)d_in[1];
  const long N = in_sizes[0] / D;      // 100000
  const long E = in_sizes[1] / 2;      // 3200000
  float* out = (float*)d_out;
  const long ND = N * D;

  uint32_t fk0[NUM_HOPS], fk1[NUM_HOPS];
  for (int k = 0; k < NUM_HOPS; ++k)
    tf2x32(0u, 42u, 0u, (uint32_t)k, &fk0[k], &fk1[k]);

  // bucket geometry: rows/bucket = 1<<shift (<=512 for fillB2 LDS), nb <= 256
  int shift = 9;
  while ((((N + ((long)1 << shift) - 1) >> shift)) > 256) shift++;
  const int nb = (int)((N + ((long)1 << shift) - 1) >> shift);
  const int bs = 1 << shift;

  // Aligned workspace carve-out
  uintptr_t base = (uintptr_t)d_ws;
  size_t off = 0;
  auto carve = [&](size_t bytes, size_t align) -> uintptr_t {
    off = align_up(off, align);
    uintptr_t p = base + off;
    off += bytes;
    return p;
  };
  int* row_ptr      = (int*)carve((size_t)(N + 1) * 4, 256);
  int* bucketCount  = (int*)carve(256 * 4, 256);
  int* bucketBase   = (int*)carve((size_t)(nb + 1) * 4, 256);
  int* bucketCursor = (int*)carve((size_t)nb * 4, 256);
  int* col          = (int*)carve((size_t)E * 4, 256);
  uint64_t* tmp     = (uint64_t*)carve((size_t)E * 8, 256);
  __half* mirA      = (__half*)carve((size_t)ND * 2, 256);
  __half* mirB      = (__half*)carve((size_t)ND * 2, 256);
  size_t need_full = off;

  long nthreads = N * 64;
  int ngrid = (int)((nthreads + 255) / 256);

  if (ws_size >= need_full && nb <= 256 && bs <= 512) {
    long epw = 256L * FILLA_EPT;
    int nblk = (int)((E + epw - 1) / epw);
    zero256_kernel<<<1, 256, 0, stream>>>(bucketCount);
    bucket_hist_kernel<<<nblk, 256, 0, stream>>>(ei, bucketCount, E, shift);
    bucket_scan_kernel<<<1, 256, 0, stream>>>(bucketCount, bucketBase, bucketCursor, nb, (int)E);
    fillA_kernel<<<nblk, 256, 0, stream>>>(ei, bucketCursor, tmp, E, shift, nb);
    fillB2_kernel<<<nb, 256, 0, stream>>>(tmp, bucketBase, row_ptr, col, shift, (int)N, nb);

    norm0_kernel<<<ngrid, 256, 0, stream>>>(x, out, mirA, (int)N);
    for (int k = 0; k < NUM_HOPS; ++k) {
      float* nxt = out + (size_t)(k + 1) * ND;
      const __half* mi = (k & 1) ? mirB : mirA;
      __half* mo       = (k & 1) ? mirA : mirB;
      gather_hop_f16<<<ngrid, 256, 0, stream>>>(mi, nxt, mo, row_ptr, col,
                                                (int)N, fk0[k], fk1[k]);
    }
  } else {
    // Fallback: proven round-3 atomic path
    norm_kernel<<<ngrid, 256, 0, stream>>>(x, out, (int)N);
    for (int k = 0; k < NUM_HOPS; ++k) {
      const float* cur = out + (size_t)k * ND;
      float* nxt = out + (size_t)(k + 1) * ND;
      noise_kernel<<<(int)((ND + 255) / 256), 256, 0, stream>>>(nxt, fk0[k], fk1[k], ND);
      long sthreads = E * 32;
      scatter_kernel<<<(int)((sthreads + 255) / 256), 256, 0, stream>>>(cur, nxt, ei, E);
      norm_kernel<<<ngrid, 256, 0, stream>>>(nxt, nxt, (int)N);
    }
  }
}